// Round 1
// baseline (567.693 us; speedup 1.0000x reference)
//
#include <hip/hip_runtime.h>
#include <math.h>

#define BN_EPS 1e-5f

// ---------------------------------------------------------------------------
// Kernel A: y = x @ pool_W   (N x 64) = (N x 64)(64 x 64)
// ---------------------------------------------------------------------------
__global__ void k_gemm_pool(const float* __restrict__ x, const float* __restrict__ W,
                            float* __restrict__ y, int nrows) {
    __shared__ float sW[64 * 64];
    __shared__ float sx[4][65];          // +1 pad: rg-broadcast across banks
    for (int i = threadIdx.x; i < 64 * 64; i += 256) sW[i] = W[i];
    const int c = threadIdx.x & 63;
    const int rg = threadIdx.x >> 6;     // 0..3 rows per block-iteration
    for (int base = blockIdx.x * 4; base < nrows; base += gridDim.x * 4) {
        __syncthreads();                 // covers sW load on iter 0, sx reuse after
        const int row = base + rg;
        sx[rg][c] = (row < nrows) ? x[row * 64 + c] : 0.0f;
        __syncthreads();
        if (row < nrows) {
            float acc = 0.0f;
#pragma unroll
            for (int k = 0; k < 64; ++k) acc = fmaf(sx[rg][k], sW[k * 64 + c], acc);
            y[row * 64 + c] = acc;
        }
    }
}

// ---------------------------------------------------------------------------
// Kernel B: per-node edge-scale sums: cnt1[n] = sum s_e, cnt2[n] = sum s_e^2
// ---------------------------------------------------------------------------
__global__ void k_edge_counts(const int* __restrict__ src, const float* __restrict__ w,
                              const float* __restrict__ coef_p,
                              float* __restrict__ cnt1, float* __restrict__ cnt2, int E) {
    const float coef = *coef_p;
    const int i = blockIdx.x * blockDim.x + threadIdx.x;
    if (i < E) {
        const float s = fmaf(coef, w[i], 1.0f);
        const int n = src[i];
        atomicAdd(&cnt1[n], s);
        atomicAdd(&cnt2[n], s * s);
    }
}

// ---------------------------------------------------------------------------
// Kernel C: S[c]    = sum_n cnt1[n]*y[n][c]      (= sum_e s_e * y[src_e][c])
//           S[64+c] = sum_n cnt2[n]*y[n][c]^2    (= sum_e s_e^2 * y[src_e][c]^2)
// ---------------------------------------------------------------------------
__global__ void k_node_stats(const float* __restrict__ y, const float* __restrict__ cnt1,
                             const float* __restrict__ cnt2, float* __restrict__ S, int nrows) {
    const int c = threadIdx.x & 63;
    const int rg = threadIdx.x >> 6;
    float s1 = 0.0f, s2 = 0.0f;
    for (int row = blockIdx.x * 4 + rg; row < nrows; row += gridDim.x * 4) {
        const float c1 = cnt1[row], c2 = cnt2[row];
        const float v = y[row * 64 + c];
        s1 = fmaf(c1, v, s1);
        s2 = fmaf(c2 * v, v, s2);
    }
    __shared__ float red[256];
    red[threadIdx.x] = s1; __syncthreads();
    if (rg == 0) atomicAdd(&S[c], red[c] + red[c + 64] + red[c + 128] + red[c + 192]);
    __syncthreads();
    red[threadIdx.x] = s2; __syncthreads();
    if (rg == 0) atomicAdd(&S[64 + c], red[c] + red[c + 64] + red[c + 128] + red[c + 192]);
}

// ---------------------------------------------------------------------------
// Kernel D: per-edge  v_c = relu(a_c * s_e * y[src_e][c] + d_c)
//           agg[dst_e][c] = max(agg, v_c)   via int-reinterpret atomicMax
// 16 threads per edge, float4 per thread (4 channels).
// ---------------------------------------------------------------------------
__global__ void k_edge_pass(const float* __restrict__ y, const int* __restrict__ src,
                            const int* __restrict__ dst, const float* __restrict__ w,
                            const float* __restrict__ S, const float* __restrict__ pool_b,
                            const float* __restrict__ gamma, const float* __restrict__ beta,
                            const float* __restrict__ coef_p,
                            int* __restrict__ agg, int E) {
    const float coef = *coef_p;
    const float invE = 1.0f / (float)E;
    const int c0 = (threadIdx.x & 15) * 4;
    float a[4], d[4];
#pragma unroll
    for (int j = 0; j < 4; ++j) {
        const int c = c0 + j;
        const float s1 = S[c] * invE;                 // mean of s*y component
        const float b = pool_b[c];
        const float mean = s1 + b;
        const float ex2 = S[64 + c] * invE + 2.0f * b * s1 + b * b;
        const float var = ex2 - mean * mean;
        const float ac = gamma[c] * rsqrtf(var + BN_EPS);
        a[j] = ac;
        d[j] = beta[c] - ac * s1;   // a*(s*y+b) + (beta - a*mean) == a*s*y + d
    }
    const float* aggf = (const float*)agg;
    const int group = (blockIdx.x * blockDim.x + threadIdx.x) >> 4;
    const int ngroups = (gridDim.x * blockDim.x) >> 4;
    for (int e = group; e < E; e += ngroups) {
        const int sn = src[e];
        const int tn = dst[e];
        const float sc = fmaf(coef, w[e], 1.0f);
        const float4 v = *(const float4*)(y + (size_t)sn * 64 + c0);
        const float p0 = fmaxf(fmaf(a[0] * sc, v.x, d[0]), 0.0f);
        const float p1 = fmaxf(fmaf(a[1] * sc, v.y, d[1]), 0.0f);
        const float p2 = fmaxf(fmaf(a[2] * sc, v.z, d[2]), 0.0f);
        const float p3 = fmaxf(fmaf(a[3] * sc, v.w, d[3]), 0.0f);
        // pre-read: only atomic when we'd actually raise the max (racy-safe: monotonic)
        const float4 cur = *(const float4*)(aggf + (size_t)tn * 64 + c0);
        int* ap = agg + (size_t)tn * 64 + c0;
        if (p0 > cur.x) atomicMax(ap + 0, __float_as_int(p0));
        if (p1 > cur.y) atomicMax(ap + 1, __float_as_int(p1));
        if (p2 > cur.z) atomicMax(ap + 2, __float_as_int(p2));
        if (p3 > cur.w) atomicMax(ap + 3, __float_as_int(p3));
    }
}

// ---------------------------------------------------------------------------
// Kernel E: h = x @ W[:64] + agg @ W[64:] + b ; accumulate per-channel sum/sumsq
// ---------------------------------------------------------------------------
__global__ void k_final_gemm(const float* __restrict__ x, const float* __restrict__ agg,
                             const float* __restrict__ W, const float* __restrict__ b,
                             float* __restrict__ h, float* __restrict__ hstat, int nrows) {
    __shared__ float sW[128 * 64];       // 32 KB
    __shared__ float sx[4][65];
    __shared__ float sa[4][65];
    __shared__ float red[256];
    for (int i = threadIdx.x; i < 128 * 64; i += 256) sW[i] = W[i];
    const int c = threadIdx.x & 63;
    const int rg = threadIdx.x >> 6;
    float lsum = 0.0f, lsq = 0.0f;
    for (int base = blockIdx.x * 4; base < nrows; base += gridDim.x * 4) {
        __syncthreads();
        const int row = base + rg;
        if (row < nrows) {
            sx[rg][c] = x[(size_t)row * 64 + c];
            sa[rg][c] = agg[(size_t)row * 64 + c];
        }
        __syncthreads();
        if (row < nrows) {
            float acc = b[c];
#pragma unroll
            for (int k = 0; k < 64; ++k) acc = fmaf(sx[rg][k], sW[k * 64 + c], acc);
#pragma unroll
            for (int k = 0; k < 64; ++k) acc = fmaf(sa[rg][k], sW[(64 + k) * 64 + c], acc);
            h[(size_t)row * 64 + c] = acc;
            lsum += acc;
            lsq = fmaf(acc, acc, lsq);
        }
    }
    __syncthreads();
    red[threadIdx.x] = lsum; __syncthreads();
    if (rg == 0) atomicAdd(&hstat[c], red[c] + red[c + 64] + red[c + 128] + red[c + 192]);
    __syncthreads();
    red[threadIdx.x] = lsq; __syncthreads();
    if (rg == 0) atomicAdd(&hstat[64 + c], red[c] + red[c + 64] + red[c + 128] + red[c + 192]);
}

// ---------------------------------------------------------------------------
// Kernel F: out = relu(bn_final(h)) using accumulated stats
// ---------------------------------------------------------------------------
__global__ void k_bn_out(const float* __restrict__ h, const float* __restrict__ hstat,
                         const float* __restrict__ gamma, const float* __restrict__ beta,
                         float* __restrict__ out, int nrows) {
    const int idx = blockIdx.x * blockDim.x + threadIdx.x;   // one float4 each
    const int total = nrows * 16;
    if (idx >= total) return;
    const int c0 = (idx & 15) * 4;
    const float invN = 1.0f / (float)nrows;
    const float4 hv = *(const float4*)(h + (size_t)idx * 4);
    float4 o;
    float* op = (float*)&o;
    const float* hp = (const float*)&hv;
#pragma unroll
    for (int j = 0; j < 4; ++j) {
        const int c = c0 + j;
        const float mean = hstat[c] * invN;
        const float var = hstat[64 + c] * invN - mean * mean;
        const float a = gamma[c] * rsqrtf(var + BN_EPS);
        const float dd = beta[c] - a * mean;
        op[j] = fmaxf(fmaf(a, hp[j], dd), 0.0f);
    }
    *(float4*)(out + (size_t)idx * 4) = o;
}

// ---------------------------------------------------------------------------
extern "C" void kernel_launch(void* const* d_in, const int* in_sizes, int n_in,
                              void* d_out, int out_size, void* d_ws, size_t ws_size,
                              hipStream_t stream) {
    const float* x       = (const float*)d_in[0];
    const int*   eidx    = (const int*)d_in[1];
    const float* ew      = (const float*)d_in[2];
    const float* pool_W  = (const float*)d_in[3];
    const float* pool_b  = (const float*)d_in[4];
    const float* g1      = (const float*)d_in[5];
    const float* b1      = (const float*)d_in[6];
    const float* final_W = (const float*)d_in[7];
    const float* final_b = (const float*)d_in[8];
    const float* g2      = (const float*)d_in[9];
    const float* b2      = (const float*)d_in[10];
    const float* coef    = (const float*)d_in[11];

    const int N = in_sizes[0] / 64;
    const int E = in_sizes[1] / 2;
    const int* src = eidx;
    const int* dst = eidx + E;

    // workspace layout (floats): [agg N*64][cnt1 N][cnt2 N][S 128][hstat 128][y N*64][h N*64]
    float* ws    = (float*)d_ws;
    int*   agg   = (int*)ws;
    float* cnt1  = ws + (size_t)N * 64;
    float* cnt2  = cnt1 + N;
    float* S     = cnt2 + N;
    float* hstat = S + 128;
    float* y     = hstat + 128;
    float* h     = y + (size_t)N * 64;

    const size_t zero_elems = (size_t)N * 64 + 2 * (size_t)N + 256;
    hipMemsetAsync(d_ws, 0, zero_elems * sizeof(float), stream);

    k_gemm_pool <<<1024, 256, 0, stream>>>(x, pool_W, y, N);
    k_edge_counts<<<(E + 255) / 256, 256, 0, stream>>>(src, ew, coef, cnt1, cnt2, E);
    k_node_stats<<<1024, 256, 0, stream>>>(y, cnt1, cnt2, S, N);
    k_edge_pass <<<4096, 256, 0, stream>>>(y, src, dst, ew, S, pool_b, g1, b1, coef, agg, E);
    k_final_gemm<<<1024, 256, 0, stream>>>(x, (const float*)agg, final_W, final_b, h, hstat, N);
    k_bn_out    <<<(N * 16 + 255) / 256, 256, 0, stream>>>(h, hstat, g2, b2, (float*)d_out, N);
}